// Round 4
// baseline (1401.941 us; speedup 1.0000x reference)
//
#include <hip/hip_runtime.h>

#define NN 100000
#define EE 3200000
#define DD 256
#define CC 40
#define NCH 16
#define CH 16
#define NGRP (NN / 4)
#define BLKS_PER_PHASE (NGRP * 8)
#define UN 16
#define UN2 8

__device__ __forceinline__ float bf2f(unsigned int u) {
    return __uint_as_float(u << 16);
}
__device__ __forceinline__ unsigned short f2bf(float f) {
    unsigned int t = __float_as_uint(f);
    return (unsigned short)((t + 0x7FFFu + ((t >> 16) & 1u)) >> 16);
}

// ---------------- CSR row_ptr from sorted adj_row ----------------
__global__ __launch_bounds__(256) void k_row_ptr(const int* __restrict__ adj_row,
                                                 int* __restrict__ row_ptr) {
    int e = blockIdx.x * 256 + threadIdx.x;
    if (e >= EE) return;
    int r = adj_row[e];
    int prev = (e == 0) ? -1 : adj_row[e - 1];
    for (int rr = prev + 1; rr <= r; ++rr) row_ptr[rr] = e;
    if (e == EE - 1) {
        for (int rr = r + 1; rr <= NN; ++rr) row_ptr[rr] = EE;
    }
}

// ---------- transpose-convert x[NN][256] f32 -> xb[16][NN][16] bf16 ----------
__global__ __launch_bounds__(256) void k_cvt_t(const float* __restrict__ x,
                                               ushort* __restrict__ xb) {
    int t = blockIdx.x * 256 + threadIdx.x;   // grid covers NN*NCH exactly
    int r = t >> 4, c = t & 15;
    const float4* src = (const float4*)(x + (size_t)r * DD + c * CH);
    float4 v0 = src[0], v1 = src[1], v2 = src[2], v3 = src[3];
    uint4 q0, q1;
    q0.x = f2bf(v0.x) | ((unsigned)f2bf(v0.y) << 16);
    q0.y = f2bf(v0.z) | ((unsigned)f2bf(v0.w) << 16);
    q0.z = f2bf(v1.x) | ((unsigned)f2bf(v1.y) << 16);
    q0.w = f2bf(v1.z) | ((unsigned)f2bf(v1.w) << 16);
    q1.x = f2bf(v2.x) | ((unsigned)f2bf(v2.y) << 16);
    q1.y = f2bf(v2.z) | ((unsigned)f2bf(v2.w) << 16);
    q1.z = f2bf(v3.x) | ((unsigned)f2bf(v3.y) << 16);
    q1.w = f2bf(v3.z) | ((unsigned)f2bf(v3.w) << 16);
    uint4* dst = (uint4*)(xb + ((size_t)c * NN + r) * CH);
    dst[0] = q0;
    dst[1] = q1;
}

// ---------- chunked SpMM1 + relu + dropout -> h (bf16, row-major) ----------
// Block = 4 waves = 4 rows, one 16-dim chunk. blockIdx%8 == chunk%8 -> XCD
// affinity; two phases so each XCD's L2 holds one 3.2MB chunk at a time.
// Wave: lane pair (eo=lane>>1, half=lane&1) loads 16B (8 dims) of edge eo's
// x-row-chunk -> 32 edges per single 1KB gather; shfl_xor tree sums edges.
__global__ __launch_bounds__(256) void k_chunk(
    const ushort* __restrict__ xb, const float* __restrict__ adj_vals,
    const int* __restrict__ adj_col, const int* __restrict__ row_ptr,
    const float* __restrict__ drop_mask, ushort* __restrict__ hb)
{
    int wave = threadIdx.x >> 6;
    int lane = threadIdx.x & 63;
    int bid = blockIdx.x;
    int phase = bid >= BLKS_PER_PHASE;
    int rr = bid - phase * BLKS_PER_PHASE;
    int sc = rr & 7;
    int grp = rr >> 3;
    int c = phase * 8 + sc;
    int row = grp * 4 + wave;

    int e0 = __builtin_amdgcn_readfirstlane(row_ptr[row]);
    int e1 = __builtin_amdgcn_readfirstlane(row_ptr[row + 1]);

    const ushort* base = xb + (size_t)c * NN * CH;
    int half = lane & 1, eo = lane >> 1;

    float acc[8] = {0.f, 0.f, 0.f, 0.f, 0.f, 0.f, 0.f, 0.f};
    for (int bb = e0; bb < e1; bb += 32) {
        int e = bb + eo;
        bool ok = e < e1;
        e = ok ? e : e1 - 1;
        float v = ok ? __builtin_nontemporal_load(adj_vals + e) : 0.f;
        int col = __builtin_nontemporal_load(adj_col + e);
        uint4 d = *(const uint4*)(base + (size_t)col * CH + half * 8);
        acc[0] = fmaf(v, bf2f(d.x & 0xFFFFu), acc[0]);
        acc[1] = fmaf(v, bf2f(d.x >> 16), acc[1]);
        acc[2] = fmaf(v, bf2f(d.y & 0xFFFFu), acc[2]);
        acc[3] = fmaf(v, bf2f(d.y >> 16), acc[3]);
        acc[4] = fmaf(v, bf2f(d.z & 0xFFFFu), acc[4]);
        acc[5] = fmaf(v, bf2f(d.z >> 16), acc[5]);
        acc[6] = fmaf(v, bf2f(d.w & 0xFFFFu), acc[6]);
        acc[7] = fmaf(v, bf2f(d.w >> 16), acc[7]);
    }
#pragma unroll
    for (int j = 0; j < 8; ++j) acc[j] += __shfl_xor(acc[j], 2);
#pragma unroll
    for (int j = 0; j < 8; ++j) acc[j] += __shfl_xor(acc[j], 4);
#pragma unroll
    for (int j = 0; j < 8; ++j) acc[j] += __shfl_xor(acc[j], 8);
#pragma unroll
    for (int j = 0; j < 8; ++j) acc[j] += __shfl_xor(acc[j], 16);
#pragma unroll
    for (int j = 0; j < 8; ++j) acc[j] += __shfl_xor(acc[j], 32);

    if (lane < 2) {   // lane0: dims c*16+0..7, lane1: dims c*16+8..15
        const float4* mp =
            (const float4*)(drop_mask + (size_t)row * DD + c * CH + half * 8);
        float4 m0 = mp[0], m1 = mp[1];
        uint4 q;
        q.x = f2bf(fmaxf(acc[0], 0.f) * m0.x * 2.f) |
              ((unsigned)f2bf(fmaxf(acc[1], 0.f) * m0.y * 2.f) << 16);
        q.y = f2bf(fmaxf(acc[2], 0.f) * m0.z * 2.f) |
              ((unsigned)f2bf(fmaxf(acc[3], 0.f) * m0.w * 2.f) << 16);
        q.z = f2bf(fmaxf(acc[4], 0.f) * m1.x * 2.f) |
              ((unsigned)f2bf(fmaxf(acc[5], 0.f) * m1.y * 2.f) << 16);
        q.w = f2bf(fmaxf(acc[6], 0.f) * m1.z * 2.f) |
              ((unsigned)f2bf(fmaxf(acc[7], 0.f) * m1.w * 2.f) << 16);
        *(uint4*)(hb + (size_t)row * DD + c * CH + half * 8) = q;
    }
}

// ---------- Linear(256->40): z = h @ W^T + b, h bf16 row-major ----------
__global__ __launch_bounds__(256) void k_linear(
    const ushort* __restrict__ hb, const float* __restrict__ W,
    const float* __restrict__ b, float* __restrict__ z)
{
    __shared__ float hs[4][DD];
    int wave = threadIdx.x >> 6, lane = threadIdx.x & 63;
    int row = blockIdx.x * 4 + wave;
    if (lane < 32) {
        uint4 d = *(const uint4*)(hb + (size_t)row * DD + lane * 8);
        float* hw = hs[wave] + lane * 8;
        hw[0] = bf2f(d.x & 0xFFFFu); hw[1] = bf2f(d.x >> 16);
        hw[2] = bf2f(d.y & 0xFFFFu); hw[3] = bf2f(d.y >> 16);
        hw[4] = bf2f(d.z & 0xFFFFu); hw[5] = bf2f(d.z >> 16);
        hw[6] = bf2f(d.w & 0xFFFFu); hw[7] = bf2f(d.w >> 16);
    }
    __syncthreads();
    if (lane < CC) {
        const float4* wr = (const float4*)(W + (size_t)lane * DD);
        const float4* hv = (const float4*)hs[wave];
        float4 p = {0.f, 0.f, 0.f, 0.f};
#pragma unroll 8
        for (int k = 0; k < DD / 4; ++k) {
            float4 wk = wr[k];
            float4 hk = hv[k];
            p.x = fmaf(hk.x, wk.x, p.x);
            p.y = fmaf(hk.y, wk.y, p.y);
            p.z = fmaf(hk.z, wk.z, p.z);
            p.w = fmaf(hk.w, wk.w, p.w);
        }
        z[(size_t)row * CC + lane] = p.x + p.y + p.z + p.w + b[lane];
    }
}

// ---------------- out = SpMM(z), z [NN,40] f32 (cache-hot) ----------------
__global__ __launch_bounds__(256) void k_spmm2(
    const float* __restrict__ z, const float* __restrict__ adj_vals,
    const int* __restrict__ adj_col, const int* __restrict__ row_ptr,
    float* __restrict__ out)
{
    int wave = threadIdx.x >> 6;
    int lane = threadIdx.x & 63;
    int row = blockIdx.x * 4 + wave;
    int cl = lane < CC ? lane : CC - 1;

    int e0 = __builtin_amdgcn_readfirstlane(row_ptr[row]);
    int e1 = __builtin_amdgcn_readfirstlane(row_ptr[row + 1]);

    float acc = 0.f;
    int nb = (e1 - e0 + UN2 - 1) / UN2;
    for (int bI = 0; bI < nb; ++bI) {
        int base = e0 + bI * UN2;
        float vv[UN2]; int cc[UN2];
#pragma unroll
        for (int u = 0; u < UN2; ++u) {
            int idx = base + u;
            bool ok = idx < e1;
            idx = ok ? idx : e1 - 1;
            vv[u] = ok ? adj_vals[idx] : 0.f;
            cc[u] = adj_col[idx];
        }
        float za[UN2];
#pragma unroll
        for (int u = 0; u < UN2; ++u)
            za[u] = z[(size_t)cc[u] * CC + cl];
#pragma unroll
        for (int u = 0; u < UN2; ++u)
            acc = fmaf(vv[u], za[u], acc);
    }
    if (lane < CC) out[(size_t)row * CC + lane] = acc;
}

// ================= fallback path (round-3 proven), used if ws too small ======
__global__ __launch_bounds__(256) void k_cvt(const float* __restrict__ x,
                                             ushort* __restrict__ xbl) {
    const int total = NN * DD / 4;
    for (int i = blockIdx.x * 256 + threadIdx.x; i < total; i += gridDim.x * 256) {
        float4 v = ((const float4*)x)[i];
        ushort4 o;
        o.x = f2bf(v.x); o.y = f2bf(v.y); o.z = f2bf(v.z); o.w = f2bf(v.w);
        ((ushort4*)xbl)[i] = o;
    }
}

__global__ __launch_bounds__(256) void k_spmm1_lin(
    const ushort* __restrict__ xbl, const float* __restrict__ adj_vals,
    const int* __restrict__ adj_col, const int* __restrict__ row_ptr,
    const float* __restrict__ drop_mask, const float* __restrict__ W,
    const float* __restrict__ b, float* __restrict__ z)
{
    int wave = threadIdx.x >> 6;
    int lane = threadIdx.x & 63;
    int row = blockIdx.x * 4 + wave;

    int e0 = __builtin_amdgcn_readfirstlane(row_ptr[row]);
    int e1 = __builtin_amdgcn_readfirstlane(row_ptr[row + 1]);
    const ushort4* xb4 = (const ushort4*)xbl;

    float4 acc = {0.f, 0.f, 0.f, 0.f};
    int nb = (e1 - e0 + UN - 1) / UN;
    for (int bI = 0; bI < nb; ++bI) {
        int base = e0 + bI * UN;
        float vv[UN]; int cc[UN];
#pragma unroll
        for (int u = 0; u < UN; ++u) {
            int idx = base + u;
            bool ok = idx < e1;
            idx = ok ? idx : e1 - 1;
            vv[u] = ok ? adj_vals[idx] : 0.f;
            cc[u] = adj_col[idx];
        }
        ushort4 xa[UN];
#pragma unroll
        for (int u = 0; u < UN; ++u)
            xa[u] = xb4[(size_t)cc[u] * (DD / 4) + lane];
#pragma unroll
        for (int u = 0; u < UN; ++u) {
            acc.x = fmaf(vv[u], bf2f(xa[u].x), acc.x);
            acc.y = fmaf(vv[u], bf2f(xa[u].y), acc.y);
            acc.z = fmaf(vv[u], bf2f(xa[u].z), acc.z);
            acc.w = fmaf(vv[u], bf2f(xa[u].w), acc.w);
        }
    }
    float4 mm = ((const float4*)drop_mask)[(size_t)row * (DD / 4) + lane];
    float4 h;
    h.x = fmaxf(acc.x, 0.f) * mm.x * 2.f;
    h.y = fmaxf(acc.y, 0.f) * mm.y * 2.f;
    h.z = fmaxf(acc.z, 0.f) * mm.z * 2.f;
    h.w = fmaxf(acc.w, 0.f) * mm.w * 2.f;

    __shared__ float hs[4][DD];
    ((float4*)hs[wave])[lane] = h;

    if (lane < CC) {
        const float4* wr = (const float4*)(W + (size_t)lane * DD);
        const float4* hv = (const float4*)hs[wave];
        float4 p = {0.f, 0.f, 0.f, 0.f};
#pragma unroll 8
        for (int k = 0; k < DD / 4; ++k) {
            float4 wk = wr[k];
            float4 hk = hv[k];
            p.x = fmaf(hk.x, wk.x, p.x);
            p.y = fmaf(hk.y, wk.y, p.y);
            p.z = fmaf(hk.z, wk.z, p.z);
            p.w = fmaf(hk.w, wk.w, p.w);
        }
        z[(size_t)row * CC + lane] = p.x + p.y + p.z + p.w + b[lane];
    }
}

extern "C" void kernel_launch(void* const* d_in, const int* in_sizes, int n_in,
                              void* d_out, int out_size, void* d_ws, size_t ws_size,
                              hipStream_t stream) {
    const float* x         = (const float*)d_in[0];
    const float* adj_vals  = (const float*)d_in[1];
    const float* W         = (const float*)d_in[2];
    const float* b         = (const float*)d_in[3];
    const float* drop_mask = (const float*)d_in[4];
    const int*   adj_row   = (const int*)d_in[5];
    const int*   adj_col   = (const int*)d_in[6];
    float* out = (float*)d_out;

    // ws: row_ptr | z | xb | hb
    char* wsp = (char*)d_ws;
    size_t rp_bytes = ((size_t)(NN + 1) * 4 + 255) & ~(size_t)255;
    size_t z_bytes  = (size_t)NN * CC * 4;
    size_t xb_bytes = (size_t)NN * DD * 2;
    size_t need_main = rp_bytes + z_bytes + 2 * xb_bytes;

    int* row_ptr = (int*)wsp;
    float* zbuf  = (float*)(wsp + rp_bytes);
    ushort* xb   = (ushort*)(wsp + rp_bytes + z_bytes);
    ushort* hb   = (ushort*)(wsp + rp_bytes + z_bytes + xb_bytes);

    hipLaunchKernelGGL(k_row_ptr, dim3((EE + 255) / 256), dim3(256), 0, stream,
                       adj_row, row_ptr);

    if (ws_size >= need_main) {
        hipLaunchKernelGGL(k_cvt_t, dim3(NN * NCH / 256), dim3(256), 0, stream,
                           x, xb);
        hipLaunchKernelGGL(k_chunk, dim3(2 * BLKS_PER_PHASE), dim3(256), 0, stream,
                           xb, adj_vals, adj_col, row_ptr, drop_mask, hb);
        hipLaunchKernelGGL(k_linear, dim3(NN / 4), dim3(256), 0, stream,
                           hb, W, b, zbuf);
    } else {
        hipLaunchKernelGGL(k_cvt, dim3(1024), dim3(256), 0, stream, x, xb);
        hipLaunchKernelGGL(k_spmm1_lin, dim3(NN / 4), dim3(256), 0, stream,
                           xb, adj_vals, adj_col, row_ptr, drop_mask, W, b, zbuf);
    }
    hipLaunchKernelGGL(k_spmm2, dim3(NN / 4), dim3(256), 0, stream,
                       zbuf, adj_vals, adj_col, row_ptr, out);
}